// Round 1
// baseline (677.685 us; speedup 1.0000x reference)
//
#include <hip/hip_runtime.h>
#include <math.h>

#define DD 128
#define SS 1024
#define NROWS 8192
#define EPSF 1e-7f
#define LN_EPSF 1e-3f
#define TCUT 30.0f

// ---------------- K1: q' = x@Wq+bq+EPS, m = sigmoid(x@Wm+bm), row scalars ----
__global__ __launch_bounds__(128) void k1_pre(
    const float* __restrict__ x,
    const float* __restrict__ Wq, const float* __restrict__ bq,
    const float* __restrict__ Wm, const float* __restrict__ bm,
    const float* __restrict__ Ww, const float* __restrict__ bw,
    const float* __restrict__ Wc, const float* __restrict__ bc,
    float* __restrict__ mq, float* __restrict__ mo, float* __restrict__ scal)
{
    int row = blockIdx.x;
    int d = threadIdx.x;
    __shared__ float sx[DD];
    __shared__ float4 red[DD];
    sx[d] = x[row * DD + d];
    __syncthreads();
    float accq = bq[d], accm = bm[d];
#pragma unroll 4
    for (int k = 0; k < DD; ++k) {
        float xv = sx[k];
        accq = fmaf(xv, Wq[k * DD + d], accq);
        accm = fmaf(xv, Wm[k * DD + d], accm);
    }
    float qp = accq + EPSF;
    float mv = 1.0f / (1.0f + expf(-accm));
    mq[row * DD + d] = mv * qp;
    mo[row * DD + d] = mv;
    float pw = sx[d] * Ww[d];
    float pc = sx[d] * Wc[d];
    red[d] = make_float4(qp, qp * qp, pw, pc);
    __syncthreads();
    for (int s = 64; s > 0; s >>= 1) {
        if (d < s) {
            float4 a = red[d], b = red[d + s];
            red[d] = make_float4(a.x + b.x, a.y + b.y, a.z + b.z, a.w + b.w);
        }
        __syncthreads();
    }
    if (d == 0) {
        float4 r = red[0];
        float wv = fmaxf(r.z + bw[0], 0.0f);
        float cv = fmaxf(r.w + bc[0], 0.0f);
        scal[row * 4 + 0] = wv;
        scal[row * 4 + 1] = cv;
        scal[row * 4 + 2] = r.x;          // sum(q')
        scal[row * 4 + 3] = sqrtf(r.y);   // ||q'||
    }
}

// ---------------- K2: windowed pair loop -> qr ------------------------------
__global__ __launch_bounds__(256) void k2_qr(
    const float* __restrict__ x,
    const float* __restrict__ mq, const float* __restrict__ mo,
    const float* __restrict__ scal, float* __restrict__ qr)
{
    int row = blockIdx.x;
    int i = row & (SS - 1);
    const float* xb = x + (size_t)(row - i) * DD;   // batch base
    int lane = threadIdx.x & 63;
    int wave = threadIdx.x >> 6;

    float mq0 = mq[row * DD + lane], mq1 = mq[row * DD + lane + 64];
    float mi0 = mo[row * DD + lane], mi1 = mo[row * DD + lane + 64];
    float wv = scal[row * 4 + 0], cv = scal[row * 4 + 1];
    float sumqp = scal[row * 4 + 2], nb = scal[row * 4 + 3];
    float wi = wv + EPSF;
    float dmaxf = cv + TCUT * wi;
    int dmax = (dmaxf >= (float)i) ? i : (int)dmaxf;

    float acc0 = 0.0f, acc1 = 0.0f;
    for (int dist = 1 + wave; dist <= dmax; dist += 4) {
        int j = i - dist;
        float x0 = xb[j * DD + lane], x1 = xb[j * DD + lane + 64];
        float t1 = x0 * mq0 + x1 * mq1;
        float xm0 = x0 * mi0, xm1 = x1 * mi1;
        float s1v = xm0 + xm1;
        float s2v = xm0 * xm0 + xm1 * xm1;
#pragma unroll
        for (int off = 32; off > 0; off >>= 1) {
            t1 += __shfl_xor(t1, off);
            s1v += __shfl_xor(s1v, off);
            s2v += __shfl_xor(s2v, off);
        }
        float t = ((float)dist - cv) / wi;
        float pe = 1.0f / coshf(t);                 // cosh->inf => pe = 0, fine
        float dotv = pe * t1 + EPSF * sumqp;
        float na = sqrtf(pe * pe * s2v + 2.0f * EPSF * pe * s1v
                         + (float)DD * EPSF * EPSF);
        float cosv = dotv / (na * nb);
        cosv = fminf(1.0f, fmaxf(-1.0f, cosv));
        float ang = acosf(cosv);
        float wgt = pe * ang;
        acc0 = fmaf(wgt, x0, acc0);
        acc1 = fmaf(wgt, x1, acc1);
    }
    __shared__ float part[4][DD];
    part[wave][lane] = acc0;
    part[wave][lane + 64] = acc1;
    __syncthreads();
    int tid = threadIdx.x;
    if (tid < DD) {
        qr[row * DD + tid] = part[0][tid] + part[1][tid] + part[2][tid] + part[3][tid];
    }
}

// ---------------- K3: mapped = (x (x) qr) @ map^T, j-split partials ---------
#define BM 64
#define BKK 32
#define JPER 32

__global__ __launch_bounds__(256) void k3_gemm(
    const float* __restrict__ x, const float* __restrict__ qr,
    const float* __restrict__ emb, float* __restrict__ part)
{
    __shared__ __align__(16) float qs[BM][132];
    __shared__ __align__(16) float bt[BKK][132];
    int rb = blockIdx.x;      // 0..127
    int js = blockIdx.y;      // 0..3
    int row0 = rb * BM;
    int tid = threadIdx.x;
    int tc = tid & 15;        // 16 column groups
    int tr = tid >> 4;        // 16 row groups
    int r0 = tr * 4;
    int d0 = tc * 4;          // cols d0..d0+3 and d0+64..d0+67

    for (int idx = tid; idx < BM * DD; idx += 256) {
        int r = idx >> 7, k = idx & 127;
        qs[r][k] = qr[(size_t)(row0 + r) * DD + k];
    }

    float acc[4][8];
#pragma unroll
    for (int a = 0; a < 4; ++a)
#pragma unroll
        for (int b = 0; b < 8; ++b) acc[a][b] = 0.0f;

    for (int jj = 0; jj < JPER; ++jj) {
        int j = js * JPER + jj;
        float xj[4];
#pragma unroll
        for (int ir = 0; ir < 4; ++ir)
            xj[ir] = x[(size_t)(row0 + r0 + ir) * DD + j];

        for (int kb = 0; kb < DD; kb += BKK) {
            __syncthreads();
            for (int idx = tid; idx < BKK * DD; idx += 256) {
                int kk = idx & 31, dd2 = idx >> 5;
                bt[kk][dd2] = emb[(size_t)dd2 * (DD * DD) + j * DD + kb + kk];
            }
            __syncthreads();

            for (int kq = 0; kq < BKK / 4; ++kq) {
                float a4[4][4];
#pragma unroll
                for (int ir = 0; ir < 4; ++ir) {
                    float4 t = *(const float4*)&qs[r0 + ir][kb + kq * 4];
                    a4[ir][0] = t.x * xj[ir];
                    a4[ir][1] = t.y * xj[ir];
                    a4[ir][2] = t.z * xj[ir];
                    a4[ir][3] = t.w * xj[ir];
                }
#pragma unroll
                for (int u = 0; u < 4; ++u) {
                    float4 b0 = *(const float4*)&bt[kq * 4 + u][d0];
                    float4 b1 = *(const float4*)&bt[kq * 4 + u][d0 + 64];
#pragma unroll
                    for (int ir = 0; ir < 4; ++ir) {
                        acc[ir][0] = fmaf(a4[ir][u], b0.x, acc[ir][0]);
                        acc[ir][1] = fmaf(a4[ir][u], b0.y, acc[ir][1]);
                        acc[ir][2] = fmaf(a4[ir][u], b0.z, acc[ir][2]);
                        acc[ir][3] = fmaf(a4[ir][u], b0.w, acc[ir][3]);
                        acc[ir][4] = fmaf(a4[ir][u], b1.x, acc[ir][4]);
                        acc[ir][5] = fmaf(a4[ir][u], b1.y, acc[ir][5]);
                        acc[ir][6] = fmaf(a4[ir][u], b1.z, acc[ir][6]);
                        acc[ir][7] = fmaf(a4[ir][u], b1.w, acc[ir][7]);
                    }
                }
            }
        }
    }

#pragma unroll
    for (int ir = 0; ir < 4; ++ir) {
        size_t rowb = ((size_t)js * NROWS + row0 + r0 + ir) * DD;
        float4 v0 = make_float4(acc[ir][0], acc[ir][1], acc[ir][2], acc[ir][3]);
        float4 v1 = make_float4(acc[ir][4], acc[ir][5], acc[ir][6], acc[ir][7]);
        *(float4*)&part[rowb + d0] = v0;
        *(float4*)&part[rowb + d0 + 64] = v1;
    }
}

// ---------------- K4: sum partials + x, LayerNorm ---------------------------
__global__ __launch_bounds__(256) void k4_ln(
    const float* __restrict__ x, const float* __restrict__ part,
    const float* __restrict__ gamma, const float* __restrict__ beta,
    float* __restrict__ out)
{
    int wave = threadIdx.x >> 6, lane = threadIdx.x & 63;
    int row = blockIdx.x * 4 + wave;
    size_t base = (size_t)row * DD;
    float r0 = x[base + lane], r1 = x[base + lane + 64];
#pragma unroll
    for (int p = 0; p < 4; ++p) {
        r0 += part[(size_t)p * NROWS * DD + base + lane];
        r1 += part[(size_t)p * NROWS * DD + base + lane + 64];
    }
    float s = r0 + r1, s2 = r0 * r0 + r1 * r1;
#pragma unroll
    for (int off = 32; off > 0; off >>= 1) {
        s += __shfl_xor(s, off);
        s2 += __shfl_xor(s2, off);
    }
    float mu = s * (1.0f / DD);
    float var = s2 * (1.0f / DD) - mu * mu;
    var = fmaxf(var, 0.0f);
    float rs = rsqrtf(var + LN_EPSF);
    out[base + lane] = (r0 - mu) * rs * gamma[lane] + beta[lane];
    out[base + lane + 64] = (r1 - mu) * rs * gamma[lane + 64] + beta[lane + 64];
}

extern "C" void kernel_launch(void* const* d_in, const int* in_sizes, int n_in,
                              void* d_out, int out_size, void* d_ws, size_t ws_size,
                              hipStream_t stream) {
    const float* x     = (const float*)d_in[0];
    const float* Wq    = (const float*)d_in[1];
    const float* bq    = (const float*)d_in[2];
    const float* Wm    = (const float*)d_in[3];
    const float* bm    = (const float*)d_in[4];
    const float* Ww    = (const float*)d_in[5];
    const float* bw    = (const float*)d_in[6];
    const float* Wc    = (const float*)d_in[7];
    const float* bc    = (const float*)d_in[8];
    const float* emb   = (const float*)d_in[9];
    const float* gamma = (const float*)d_in[10];
    const float* beta  = (const float*)d_in[11];
    float* out = (float*)d_out;
    float* ws  = (float*)d_ws;

    float* mq   = ws;                 // 1,048,576
    float* mo   = ws + 1048576;       // 1,048,576
    float* qr   = ws + 2097152;       // 1,048,576
    float* scal = ws + 3145728;       // 32,768
    float* part = ws + 3178496;       // 4 x 1,048,576

    hipLaunchKernelGGL(k1_pre, dim3(NROWS), dim3(128), 0, stream,
                       x, Wq, bq, Wm, bm, Ww, bw, Wc, bc, mq, mo, scal);
    hipLaunchKernelGGL(k2_qr, dim3(NROWS), dim3(256), 0, stream,
                       x, mq, mo, scal, qr);
    hipLaunchKernelGGL(k3_gemm, dim3(128, 4), dim3(256), 0, stream,
                       x, qr, emb, part);
    hipLaunchKernelGGL(k4_ln, dim3(2048), dim3(256), 0, stream,
                       x, part, gamma, beta, out);
}

// Round 2
// 155.218 us; speedup vs baseline: 4.3660x; 4.3660x over previous
//
#include <hip/hip_runtime.h>
#include <hip/hip_bf16.h>
#include <math.h>

#define DD 128
#define SS 1024
#define NROWS 8192
#define EPSF 1e-7f
#define LN_EPSF 1e-3f
#define TCUT 30.0f
#define JSPLIT 4
#define JPB 32

typedef __attribute__((ext_vector_type(8))) short bf16x8;
typedef __attribute__((ext_vector_type(4))) float f32x4;

__device__ __forceinline__ void gload_lds16(const void* g, void* l) {
    __builtin_amdgcn_global_load_lds(
        (const __attribute__((address_space(1))) unsigned int*)g,
        (__attribute__((address_space(3))) unsigned int*)l, 16, 0, 0);
}

__device__ __forceinline__ unsigned int pack_bf16(float lo, float hi) {
    unsigned int r;
    asm("v_cvt_pk_bf16_f32 %0, %1, %2" : "=v"(r) : "v"(lo), "v"(hi));
    return r;
}

// ---------------- K0: emb f32 -> bf16 ---------------------------------------
__global__ __launch_bounds__(256) void k0_cvt(const float* __restrict__ emb,
                                              __hip_bfloat16* __restrict__ embh) {
    int t = blockIdx.x * 256 + threadIdx.x;
    size_t base = (size_t)t * 8;
    float4 a = *(const float4*)(emb + base);
    float4 b = *(const float4*)(emb + base + 4);
    union { bf16x8 v; __hip_bfloat16 h[8]; } o;
    o.h[0] = __float2bfloat16(a.x); o.h[1] = __float2bfloat16(a.y);
    o.h[2] = __float2bfloat16(a.z); o.h[3] = __float2bfloat16(a.w);
    o.h[4] = __float2bfloat16(b.x); o.h[5] = __float2bfloat16(b.y);
    o.h[6] = __float2bfloat16(b.z); o.h[7] = __float2bfloat16(b.w);
    *(bf16x8*)((short*)embh + base) = o.v;
}

// ---------------- K1: q' = x@Wq+bq+EPS, m = sigmoid(x@Wm+bm), row scalars ----
__global__ __launch_bounds__(128) void k1_pre(
    const float* __restrict__ x,
    const float* __restrict__ Wq, const float* __restrict__ bq,
    const float* __restrict__ Wm, const float* __restrict__ bm,
    const float* __restrict__ Ww, const float* __restrict__ bw,
    const float* __restrict__ Wc, const float* __restrict__ bc,
    float* __restrict__ mq, float* __restrict__ mo, float* __restrict__ scal)
{
    int row = blockIdx.x;
    int d = threadIdx.x;
    __shared__ float sx[DD];
    __shared__ float4 red[DD];
    sx[d] = x[row * DD + d];
    __syncthreads();
    float accq = bq[d], accm = bm[d];
#pragma unroll 4
    for (int k = 0; k < DD; ++k) {
        float xv = sx[k];
        accq = fmaf(xv, Wq[k * DD + d], accq);
        accm = fmaf(xv, Wm[k * DD + d], accm);
    }
    float qp = accq + EPSF;
    float mv = 1.0f / (1.0f + expf(-accm));
    mq[row * DD + d] = mv * qp;
    mo[row * DD + d] = mv;
    float pw = sx[d] * Ww[d];
    float pc = sx[d] * Wc[d];
    red[d] = make_float4(qp, qp * qp, pw, pc);
    __syncthreads();
    for (int s = 64; s > 0; s >>= 1) {
        if (d < s) {
            float4 a = red[d], b = red[d + s];
            red[d] = make_float4(a.x + b.x, a.y + b.y, a.z + b.z, a.w + b.w);
        }
        __syncthreads();
    }
    if (d == 0) {
        float4 r = red[0];
        float wv = fmaxf(r.z + bw[0], 0.0f);
        float cv = fmaxf(r.w + bc[0], 0.0f);
        scal[row * 4 + 0] = wv;
        scal[row * 4 + 1] = cv;
        scal[row * 4 + 2] = r.x;
        scal[row * 4 + 3] = sqrtf(r.y);
    }
}

// ---------------- K2: windowed pair loop -> qr (f32) ------------------------
__global__ __launch_bounds__(256) void k2_qr(
    const float* __restrict__ x,
    const float* __restrict__ mq, const float* __restrict__ mo,
    const float* __restrict__ scal, float* __restrict__ qr)
{
    int row = blockIdx.x;
    int i = row & (SS - 1);
    const float* xb = x + (size_t)(row - i) * DD;
    int lane = threadIdx.x & 63;
    int wave = threadIdx.x >> 6;

    float mq0 = mq[row * DD + lane], mq1 = mq[row * DD + lane + 64];
    float mi0 = mo[row * DD + lane], mi1 = mo[row * DD + lane + 64];
    float wv = scal[row * 4 + 0], cv = scal[row * 4 + 1];
    float sumqp = scal[row * 4 + 2], nb = scal[row * 4 + 3];
    float wi = wv + EPSF;
    float dmaxf = cv + TCUT * wi;
    int dmax = (dmaxf >= (float)i) ? i : (int)dmaxf;

    float acc0 = 0.0f, acc1 = 0.0f;
    for (int dist = 1 + wave; dist <= dmax; dist += 4) {
        int j = i - dist;
        float x0 = xb[j * DD + lane], x1 = xb[j * DD + lane + 64];
        float t1 = x0 * mq0 + x1 * mq1;
        float xm0 = x0 * mi0, xm1 = x1 * mi1;
        float s1v = xm0 + xm1;
        float s2v = xm0 * xm0 + xm1 * xm1;
#pragma unroll
        for (int off = 32; off > 0; off >>= 1) {
            t1 += __shfl_xor(t1, off);
            s1v += __shfl_xor(s1v, off);
            s2v += __shfl_xor(s2v, off);
        }
        float t = ((float)dist - cv) / wi;
        float pe = 1.0f / coshf(t);
        float dotv = pe * t1 + EPSF * sumqp;
        float na = sqrtf(pe * pe * s2v + 2.0f * EPSF * pe * s1v
                         + (float)DD * EPSF * EPSF);
        float cosv = dotv / (na * nb);
        cosv = fminf(1.0f, fmaxf(-1.0f, cosv));
        float ang = acosf(cosv);
        float wgt = pe * ang;
        acc0 = fmaf(wgt, x0, acc0);
        acc1 = fmaf(wgt, x1, acc1);
    }
    __shared__ float part[4][DD];
    part[wave][lane] = acc0;
    part[wave][lane + 64] = acc1;
    __syncthreads();
    int tid = threadIdx.x;
    if (tid < DD) {
        qr[row * DD + tid] = part[0][tid] + part[1][tid] + part[2][tid] + part[3][tid];
    }
}

// ---------------- K3: MFMA GEMM  mapped = (x (x) qr) @ emb^T ----------------
// grid (64, JSPLIT), 256 thr (4 waves). Block: 128 rows x 128 d, 32 j's.
// wave tile 32 rows x 128 d. qr rows in registers (f32), A generated on the
// fly as bf16(x*qr); B (emb[d][j][k]) staged swizzled in LDS, double-buffered.
__global__ __launch_bounds__(256) void k3_mfma(
    const float* __restrict__ x, const float* __restrict__ qr,
    const __hip_bfloat16* __restrict__ embh, float* __restrict__ part)
{
    __shared__ short bt[2][128 * 128];   // 2 x 32 KB, swizzled bf16
    __shared__ float xt[JPB][128];       // 16 KB, xt[j][r]

    int tid = threadIdx.x;
    int w = tid >> 6, l = tid & 63;
    int l15 = l & 15, g = l >> 4;
    int row0 = blockIdx.x * 128;
    int js = blockIdx.y;
    int j0 = js * JPB;
    const short* embs = (const short*)embh;

    // stage xt: xt[j][r] = x[(row0+r)*DD + j0+j]
    for (int idx = tid; idx < JPB * 128; idx += 256) {
        int j = idx >> 7, r = idx & 127;
        xt[j][r] = x[(size_t)(row0 + r) * DD + j0 + j];
    }

    // load qr fragments to registers: wave w owns rows row0+w*32 .. +31
    float qf[2][4][8];
#pragma unroll
    for (int rf = 0; rf < 2; ++rf) {
        const float* qp = qr + (size_t)(row0 + w * 32 + rf * 16 + l15) * DD + g * 8;
#pragma unroll
        for (int s = 0; s < 4; ++s) {
            float4 u0 = *(const float4*)(qp + s * 32);
            float4 u1 = *(const float4*)(qp + s * 32 + 4);
            qf[rf][s][0] = u0.x; qf[rf][s][1] = u0.y;
            qf[rf][s][2] = u0.z; qf[rf][s][3] = u0.w;
            qf[rf][s][4] = u1.x; qf[rf][s][5] = u1.y;
            qf[rf][s][6] = u1.z; qf[rf][s][7] = u1.w;
        }
    }

    // B staging: thread handles 8 x 16B chunks per j-tile.
    // LDS linear chunk (d, c) <- global chunk (c ^ (d&7))  [inverse pre-swizzle]
    int co = tid;                 // chunk id 0..255 per round
    int sd = co >> 4;             // d-row within 16-row group per round
    auto stage = [&](int buf, int j) {
#pragma unroll
        for (int it = 0; it < 8; ++it) {
            int d = it * 16 + sd;
            int schunk = (co & 15) ^ (d & 7);
            const short* src = embs + (size_t)d * (DD * DD) + (size_t)j * DD + schunk * 8;
            short* dst = &bt[buf][(it * 256 + w * 64) * 8];   // wave-uniform base
            gload_lds16(src, dst);
        }
    };

    stage(0, j0);

    f32x4 acc[2][8];
#pragma unroll
    for (int rf = 0; rf < 2; ++rf)
#pragma unroll
        for (int cf = 0; cf < 8; ++cf)
            acc[rf][cf] = (f32x4){0.f, 0.f, 0.f, 0.f};

    int xmask = (l & 7) << 3;   // element-index XOR for swizzled read
    int ko[4];
#pragma unroll
    for (int s = 0; s < 4; ++s) ko[s] = (s * 32 + g * 8) ^ xmask;

    __syncthreads();

    for (int jj = 0; jj < JPB; ++jj) {
        int cur = jj & 1;
        if (jj < JPB - 1) stage(cur ^ 1, j0 + jj + 1);

        float xj0 = xt[jj][w * 32 + l15];
        float xj1 = xt[jj][w * 32 + 16 + l15];
        const short* bb = &bt[cur][0];

#pragma unroll
        for (int s = 0; s < 4; ++s) {
            union { bf16x8 v; unsigned int u[4]; } a0, a1;
#pragma unroll
            for (int p = 0; p < 4; ++p) {
                a0.u[p] = pack_bf16(qf[0][s][2 * p] * xj0, qf[0][s][2 * p + 1] * xj0);
                a1.u[p] = pack_bf16(qf[1][s][2 * p] * xj1, qf[1][s][2 * p + 1] * xj1);
            }
#pragma unroll
            for (int cf = 0; cf < 8; ++cf) {
                bf16x8 b = *(const bf16x8*)(bb + (cf * 16 + l15) * 128 + ko[s]);
                acc[0][cf] = __builtin_amdgcn_mfma_f32_16x16x32_bf16(a0.v, b, acc[0][cf], 0, 0, 0);
                acc[1][cf] = __builtin_amdgcn_mfma_f32_16x16x32_bf16(a1.v, b, acc[1][cf], 0, 0, 0);
            }
        }
        __syncthreads();
    }

    size_t pbase = (size_t)js * ((size_t)NROWS * DD);
#pragma unroll
    for (int rf = 0; rf < 2; ++rf) {
        int rbase = row0 + w * 32 + rf * 16 + g * 4;
#pragma unroll
        for (int cf = 0; cf < 8; ++cf) {
            int d = cf * 16 + l15;
#pragma unroll
            for (int q = 0; q < 4; ++q)
                part[pbase + (size_t)(rbase + q) * DD + d] = acc[rf][cf][q];
        }
    }
}

// ---------------- K4: sum partials + x, LayerNorm ---------------------------
__global__ __launch_bounds__(256) void k4_ln(
    const float* __restrict__ x, const float* __restrict__ part,
    const float* __restrict__ gamma, const float* __restrict__ beta,
    float* __restrict__ out)
{
    int wave = threadIdx.x >> 6, lane = threadIdx.x & 63;
    int row = blockIdx.x * 4 + wave;
    size_t base = (size_t)row * DD;
    float r0 = x[base + lane], r1 = x[base + lane + 64];
#pragma unroll
    for (int p = 0; p < JSPLIT; ++p) {
        r0 += part[(size_t)p * NROWS * DD + base + lane];
        r1 += part[(size_t)p * NROWS * DD + base + lane + 64];
    }
    float s = r0 + r1, s2 = r0 * r0 + r1 * r1;
#pragma unroll
    for (int off = 32; off > 0; off >>= 1) {
        s += __shfl_xor(s, off);
        s2 += __shfl_xor(s2, off);
    }
    float mu = s * (1.0f / DD);
    float var = s2 * (1.0f / DD) - mu * mu;
    var = fmaxf(var, 0.0f);
    float rs = rsqrtf(var + LN_EPSF);
    out[base + lane] = (r0 - mu) * rs * gamma[lane] + beta[lane];
    out[base + lane + 64] = (r1 - mu) * rs * gamma[lane + 64] + beta[lane + 64];
}

extern "C" void kernel_launch(void* const* d_in, const int* in_sizes, int n_in,
                              void* d_out, int out_size, void* d_ws, size_t ws_size,
                              hipStream_t stream) {
    const float* x     = (const float*)d_in[0];
    const float* Wq    = (const float*)d_in[1];
    const float* bq    = (const float*)d_in[2];
    const float* Wm    = (const float*)d_in[3];
    const float* bm    = (const float*)d_in[4];
    const float* Ww    = (const float*)d_in[5];
    const float* bw    = (const float*)d_in[6];
    const float* Wc    = (const float*)d_in[7];
    const float* bc    = (const float*)d_in[8];
    const float* emb   = (const float*)d_in[9];
    const float* gamma = (const float*)d_in[10];
    const float* beta  = (const float*)d_in[11];
    float* out = (float*)d_out;
    float* ws  = (float*)d_ws;

    // ws layout (float offsets):
    // embh  [0,        1048576)   4 MB as bf16 (2,097,152 shorts)
    // qr    [1048576,  2097152)   4 MB
    // scal  [2097152,  2129920)
    // mq    [2129920,  3178496)   4 MB   (dead after k2)
    // mo    [3178496,  4227072)   4 MB   (dead after k2)
    // part  [2129920,  6324224)  16 MB   (aliases mq/mo; written by k3)
    __hip_bfloat16* embh = (__hip_bfloat16*)ws;
    float* qr   = ws + 1048576;
    float* scal = ws + 2097152;
    float* mq   = ws + 2129920;
    float* mo   = ws + 3178496;
    float* part = ws + 2129920;

    hipLaunchKernelGGL(k0_cvt, dim3(1024), dim3(256), 0, stream, emb, embh);
    hipLaunchKernelGGL(k1_pre, dim3(NROWS), dim3(128), 0, stream,
                       x, Wq, bq, Wm, bm, Ww, bw, Wc, bc, mq, mo, scal);
    hipLaunchKernelGGL(k2_qr, dim3(NROWS), dim3(256), 0, stream,
                       x, mq, mo, scal, qr);
    hipLaunchKernelGGL(k3_mfma, dim3(64, JSPLIT), dim3(256), 0, stream,
                       x, qr, embh, part);
    hipLaunchKernelGGL(k4_ln, dim3(2048), dim3(256), 0, stream,
                       x, part, gamma, beta, out);
}